// Round 8
// baseline (879.038 us; speedup 1.0000x reference)
//
#include <hip/hip_runtime.h>

// GCN, 7 layers: h = relu(Â (h W) + b), Â = D^-1/2 (A + I) D^-1/2.
// Round 8: ZERO scattered global atomics (r7 evidence: each random-line
// global atomic costs a 64B HBM writeback -> k_A0's 101 MB / 146 µs).
// CSR build is now: LDS bucket histogram -> scan (deterministic ranges) ->
// staged bucket-major records -> per-bucket (512-node) block-local degree,
// offsets, and placement, all via LDS atomics + plain stores.

static constexpr int NN = 100000;
static constexpr int NE = 1600000;
static constexpr int BKL = 9;                      // 512 nodes per bucket
static constexpr int NBUK = (NN + 511) >> BKL;     // 196 buckets
static constexpr int EPT = 8;                      // edges per thread (hist/A1)
static constexpr int EB = (NE + 2047) / 2048;      // 782 edge blocks
static constexpr int SCAN_N = NBUK * EB;           // 153272

// ---------------- 1. bucket histogram (LDS only) ----------------

__global__ __launch_bounds__(256) void k_hist0(const int* __restrict__ col,
                                               int* __restrict__ counts) {
    __shared__ int lh[NBUK];
    for (int j = threadIdx.x; j < NBUK; j += 256) lh[j] = 0;
    __syncthreads();
    int base = blockIdx.x * 2048;
#pragma unroll
    for (int k = 0; k < EPT; ++k) {
        int e = base + k * 256 + threadIdx.x;
        if (e < NE) atomicAdd(&lh[col[e] >> BKL], 1);
    }
    __syncthreads();
    for (int j = threadIdx.x; j < NBUK; j += 256)
        counts[j * EB + blockIdx.x] = lh[j];  // bucket-major
}

// ---------------- 2. scan of counts -> staging offsets + bucket starts ----

__global__ __launch_bounds__(1024) void k_bbscan(int* __restrict__ counts,
                                                 int* __restrict__ bstart) {
    __shared__ int lds[1024];
    const int t = threadIdx.x;
    const int per = (SCAN_N + 1023) / 1024;  // 150
    const int base = t * per;
    int s = 0;
    for (int k = 0; k < per; ++k) {
        int idx = base + k;
        if (idx < SCAN_N) s += counts[idx];
    }
    lds[t] = s;
    __syncthreads();
    for (int off = 1; off < 1024; off <<= 1) {
        int v = (t >= off) ? lds[t - off] : 0;
        __syncthreads();
        lds[t] += v;
        __syncthreads();
    }
    int run = lds[t] - s;  // exclusive prefix of this chunk
    for (int k = 0; k < per; ++k) {
        int idx = base + k;
        if (idx < SCAN_N) { int c = counts[idx]; counts[idx] = run; run += c; }
    }
    __syncthreads();  // block-wide visibility of the global stores above
    if (t < NBUK) bstart[t] = counts[t * EB];
    if (t == 0) bstart[NBUK] = NE;
}

// ---------------- 3. stage records, bucket-grouped (LDS cursors) ----------
// record: .x = (c_local << 17) | r   (c_local<512: 9b, r<100000: 17b)
//         .y = edge weight bits

__global__ __launch_bounds__(256) void k_A1(const int* __restrict__ row,
                                            const int* __restrict__ col,
                                            const float* __restrict__ ew,
                                            const int* __restrict__ counts,
                                            int2* __restrict__ stg) {
    __shared__ int cur[NBUK];
    for (int j = threadIdx.x; j < NBUK; j += 256)
        cur[j] = counts[j * EB + blockIdx.x];
    __syncthreads();
    int base = blockIdx.x * 2048;
#pragma unroll
    for (int k = 0; k < EPT; ++k) {
        int e = base + k * 256 + threadIdx.x;
        if (e < NE) {
            int c = col[e], r = row[e];
            int pos = atomicAdd(&cur[c >> BKL], 1);  // LDS atomic
            stg[pos] = make_int2(((c & 511) << 17) | r, __float_as_int(ew[e]));
        }
    }
}

// ---------------- 4. per-bucket degree -> dinv (plain stores) ----------

__global__ __launch_bounds__(256) void k_bdeg(const int* __restrict__ bstart,
                                              const int2* __restrict__ stg,
                                              float* __restrict__ dinv) {
    __shared__ float sdeg[512];
    const int b = blockIdx.x;
    for (int j = threadIdx.x; j < 512; j += 256) sdeg[j] = 0.0f;
    __syncthreads();
    const int s = bstart[b], e = bstart[b + 1];
    for (int p = s + threadIdx.x; p < e; p += 256) {
        int2 rec = stg[p];
        atomicAdd(&sdeg[rec.x >> 17], __int_as_float(rec.y));
    }
    __syncthreads();
    for (int j = threadIdx.x; j < 512; j += 256) {
        int idx = (b << BKL) + j;
        if (idx < NN) dinv[idx] = rsqrtf(sdeg[j] + 1.0f);  // +1 self-loop
    }
}

// ---------------- 5. per-bucket placement: offs + csw (LDS scan) ----------

__global__ __launch_bounds__(512) void k_place(const int* __restrict__ bstart,
                                               const int2* __restrict__ stg,
                                               const float* __restrict__ dinv,
                                               int* __restrict__ offs,
                                               int2* __restrict__ csw) {
    __shared__ int lcnt[512];
    __shared__ int cur[512];
    const int b = blockIdx.x;
    const int t = threadIdx.x;
    lcnt[t] = 0;
    __syncthreads();
    const int s = bstart[b], e = bstart[b + 1];
    for (int p = s + t; p < e; p += 512)
        atomicAdd(&lcnt[stg[p].x >> 17], 1);
    __syncthreads();
    int v = lcnt[t];
    for (int off = 1; off < 512; off <<= 1) {   // inclusive Hillis-Steele
        int u = (t >= off) ? lcnt[t - off] : 0;
        __syncthreads();
        lcnt[t] += u;
        __syncthreads();
    }
    int excl = lcnt[t] - v;
    int idx = (b << BKL) + t;
    if (idx <= NN) offs[idx] = s + excl;        // covers offs[NN] exactly once
    cur[t] = s + excl;
    __syncthreads();
    float dc_base = (idx < NN) ? dinv[idx] : 0.0f;  // dinv[(b<<9)+t], unused below; keep loads simple
    (void)dc_base;
    for (int p = s + t; p < e; p += 512) {
        int2 rec = stg[p];
        int cl = rec.x >> 17;
        int r = rec.x & 0x1FFFF;
        float nw = dinv[r] * __int_as_float(rec.y) * dinv[(b << BKL) + cl];
        int slot = atomicAdd(&cur[cl], 1);      // LDS atomic
        csw[slot] = make_int2(r, __float_as_int(nw));
    }
}

// ---------------- dense H = X * W ----------------
// Thread per node; acc[FOUT] in VGPRs; W loop-uniform -> s_load scalar reads.

template <int FIN, int FOUT>
__global__ __launch_bounds__(256) void k_matmul(const float* __restrict__ X,
                                                const float* __restrict__ W,
                                                float* __restrict__ H) {
    int i = blockIdx.x * 256 + threadIdx.x;
    if (i >= NN) return;
    const float* xr = X + (size_t)i * FIN;
    float acc[FOUT];
#pragma unroll
    for (int j = 0; j < FOUT; ++j) acc[j] = 0.0f;

    constexpr int KV = (FIN % 4 == 0) ? 4 : 2;
    for (int k = 0; k < FIN; k += KV) {
        float xv[KV];
        if constexpr (KV == 4) *(float4*)xv = *(const float4*)(xr + k);
        else                   *(float2*)xv = *(const float2*)(xr + k);
#pragma unroll
        for (int kk = 0; kk < KV; ++kk)
#pragma unroll
            for (int j = 0; j < FOUT; ++j)
                acc[j] = fmaf(xv[kk], W[(k + kk) * FOUT + j], acc[j]);
    }
    float* hr = H + (size_t)i * FOUT;
#pragma unroll
    for (int j = 0; j < FOUT; ++j) hr[j] = acc[j];
}

template <int FIN>
__global__ void k_matmul_1(const float* __restrict__ X, const float* __restrict__ W,
                           float* __restrict__ H) {
    int i = blockIdx.x * blockDim.x + threadIdx.x;
    if (i >= NN) return;
    const float* xr = X + (size_t)i * FIN;
    float acc = 0.0f;
#pragma unroll
    for (int k = 0; k < FIN; k += 2) {
        float2 xv = *(const float2*)(xr + k);
        acc = fmaf(xv.x, W[k], acc);
        acc = fmaf(xv.y, W[k + 1], acc);
    }
    H[i] = acc;
}

// ---------------- CSR pull aggregation + fused epilogue ----------------

template <int F, int LPN, bool RELU>
__global__ __launch_bounds__(256) void k_agg2(const int* __restrict__ offs,
                                              const int2* __restrict__ csw,
                                              const float* __restrict__ H,
                                              const float* __restrict__ dinv,
                                              const float* __restrict__ b,
                                              float* __restrict__ O) {
    constexpr int FH = F / 2;
    int t = blockIdx.x * blockDim.x + threadIdx.x;
    int g = t / LPN;
    int f = t - g * LPN;           // float2 lane
    if (g >= NN || f >= FH) return;
    int p = offs[g];
    const int pe = offs[g + 1];

    float2 a0 = {0.f, 0.f}, a1 = {0.f, 0.f}, a2 = {0.f, 0.f}, a3 = {0.f, 0.f};

    if (p < pe && (p & 1)) {       // peel to even p for 16B-aligned int4 loads
        int2 e = csw[p];
        float2 h = *(const float2*)(H + (size_t)e.x * F + 2 * f);
        float w = __int_as_float(e.y);
        a0.x = fmaf(h.x, w, a0.x); a0.y = fmaf(h.y, w, a0.y);
        ++p;
    }
    for (; p + 4 <= pe; p += 4) {
        int4 e01 = *(const int4*)(csw + p);
        int4 e23 = *(const int4*)(csw + p + 2);
        float2 h0 = *(const float2*)(H + (size_t)e01.x * F + 2 * f);
        float2 h1 = *(const float2*)(H + (size_t)e01.z * F + 2 * f);
        float2 h2 = *(const float2*)(H + (size_t)e23.x * F + 2 * f);
        float2 h3 = *(const float2*)(H + (size_t)e23.z * F + 2 * f);
        float w0 = __int_as_float(e01.y), w1 = __int_as_float(e01.w);
        float w2 = __int_as_float(e23.y), w3 = __int_as_float(e23.w);
        a0.x = fmaf(h0.x, w0, a0.x); a0.y = fmaf(h0.y, w0, a0.y);
        a1.x = fmaf(h1.x, w1, a1.x); a1.y = fmaf(h1.y, w1, a1.y);
        a2.x = fmaf(h2.x, w2, a2.x); a2.y = fmaf(h2.y, w2, a2.y);
        a3.x = fmaf(h3.x, w3, a3.x); a3.y = fmaf(h3.y, w3, a3.y);
    }
    for (; p < pe; ++p) {
        int2 e = csw[p];
        float2 h = *(const float2*)(H + (size_t)e.x * F + 2 * f);
        float w = __int_as_float(e.y);
        a0.x = fmaf(h.x, w, a0.x); a0.y = fmaf(h.y, w, a0.y);
    }

    float di = dinv[g];
    float d2 = di * di;
    float2 hs = *(const float2*)(H + (size_t)g * F + 2 * f);
    float2 bb = *(const float2*)(b + 2 * f);
    float vx = ((a0.x + a1.x) + (a2.x + a3.x)) + fmaf(hs.x, d2, bb.x);
    float vy = ((a0.y + a1.y) + (a2.y + a3.y)) + fmaf(hs.y, d2, bb.y);
    if (RELU) { vx = fmaxf(vx, 0.0f); vy = fmaxf(vy, 0.0f); }
    *(float2*)(O + (size_t)g * F + 2 * f) = make_float2(vx, vy);
}

__global__ void k_agg1(const int* __restrict__ offs, const int2* __restrict__ csw,
                       const float* __restrict__ H, const float* __restrict__ dinv,
                       const float* __restrict__ b, float* __restrict__ O) {
    int g = blockIdx.x * blockDim.x + threadIdx.x;
    if (g >= NN) return;
    int p = offs[g];
    const int pe = offs[g + 1];
    float a0 = 0.f, a1 = 0.f, a2 = 0.f, a3 = 0.f;
    for (; p + 4 <= pe; p += 4) {
        int2 e0 = csw[p], e1 = csw[p + 1], e2 = csw[p + 2], e3 = csw[p + 3];
        a0 = fmaf(H[e0.x], __int_as_float(e0.y), a0);
        a1 = fmaf(H[e1.x], __int_as_float(e1.y), a1);
        a2 = fmaf(H[e2.x], __int_as_float(e2.y), a2);
        a3 = fmaf(H[e3.x], __int_as_float(e3.y), a3);
    }
    for (; p < pe; ++p) {
        int2 e0 = csw[p];
        a0 = fmaf(H[e0.x], __int_as_float(e0.y), a0);
    }
    float di = dinv[g];
    O[g] = ((a0 + a1) + (a2 + a3)) + fmaf(H[g], di * di, b[0]);
}

// ---------------- launch ----------------

static inline size_t alignup(size_t x) { return (x + 255) & ~(size_t)255; }

extern "C" void kernel_launch(void* const* d_in, const int* in_sizes, int n_in,
                              void* d_out, int out_size, void* d_ws, size_t ws_size,
                              hipStream_t stream) {
    const float* x  = (const float*)d_in[0];
    const int*   ei = (const int*)d_in[1];
    const float* ew = (const float*)d_in[2];
    const float* Wp[7];
    const float* Bp[7];
    for (int l = 0; l < 7; ++l) {
        Wp[l] = (const float*)d_in[3 + 2 * l];
        Bp[l] = (const float*)d_in[4 + 2 * l];
    }
    const int* row = ei;       // source
    const int* col = ei + NE;  // destination

    // workspace carve (~88 MB)
    char* ws = (char*)d_ws;
    float* dinv  = (float*)ws;  ws += alignup((size_t)NN * 4);
    float* Hb    = (float*)ws;  ws += alignup((size_t)NN * 50 * 4);
    float* Aa    = (float*)ws;  ws += alignup((size_t)NN * 50 * 4);
    float* Ab    = (float*)ws;  ws += alignup((size_t)NN * 50 * 4);
    int*   offs  = (int*)ws;    ws += alignup((size_t)(NN + 1) * 4);
    int*   counts= (int*)ws;    ws += alignup((size_t)SCAN_N * 4);
    int*   bstart= (int*)ws;    ws += alignup((size_t)(NBUK + 1) * 4);
    int2*  stg   = (int2*)ws;   ws += alignup((size_t)NE * 8);
    int2*  csw   = (int2*)ws;   ws += alignup((size_t)NE * 8);

    const int gN = (NN + 255) / 256;

    // CSR build — no global atomics anywhere
    k_hist0<<<EB, 256, 0, stream>>>(col, counts);
    k_bbscan<<<1, 1024, 0, stream>>>(counts, bstart);
    k_A1<<<EB, 256, 0, stream>>>(row, col, ew, counts, stg);
    k_bdeg<<<NBUK, 256, 0, stream>>>(bstart, stg, dinv);
    k_place<<<NBUK, 512, 0, stream>>>(bstart, stg, dinv, offs, csw);

#define LAYER(FIN, FOUT, LPN, RELU, XIN, OUT, LIDX)                                         \
    do {                                                                                    \
        k_matmul<FIN, FOUT><<<gN, 256, 0, stream>>>((XIN), Wp[LIDX], Hb);                   \
        k_agg2<FOUT, LPN, RELU><<<((size_t)NN * (LPN) + 255) / 256, 256, 0, stream>>>(      \
            offs, csw, Hb, dinv, Bp[LIDX], (OUT));                                          \
    } while (0)

    LAYER(128, 50, 32, true, x,  Aa, 0);
    LAYER(50,  50, 32, true, Aa, Ab, 1);
    LAYER(50,  30, 16, true, Ab, Aa, 2);
    LAYER(30,  30, 16, true, Aa, Ab, 3);
    LAYER(30,  10, 8,  true, Ab, Aa, 4);
    LAYER(10,  10, 8,  true, Aa, Ab, 5);
#undef LAYER

    // layer 7: 10 -> 1, no relu
    k_matmul_1<10><<<gN, 256, 0, stream>>>(Ab, Wp[6], Hb);
    k_agg1<<<gN, 256, 0, stream>>>(offs, csw, Hb, dinv, Bp[6], (float*)d_out);
}

// Round 9
// 596.647 us; speedup vs baseline: 1.4733x; 1.4733x over previous
//
#include <hip/hip_runtime.h>

// GCN, 7 layers: h = relu(Â (h W) + b), Â = D^-1/2 (A + I) D^-1/2.
// Round 9: r8's single-block 153K scan (300 µs, 0.19% occupancy) replaced by
// a hierarchical scan: 196 parallel per-bucket scans + one 196-element scan.
// CSR build remains zero-global-atomic (r7 lesson: scattered global atomics
// cost a 64B HBM writeback per op).

static constexpr int NN = 100000;
static constexpr int NE = 1600000;
static constexpr int BKL = 9;                      // 512 nodes per bucket
static constexpr int NBUK = (NN + 511) >> BKL;     // 196 buckets
static constexpr int EPT = 8;                      // edges per thread (hist/A1)
static constexpr int EB = (NE + 2047) / 2048;      // 782 edge blocks

// ---------------- 1. bucket histogram (LDS only) ----------------

__global__ __launch_bounds__(256) void k_hist0(const int* __restrict__ col,
                                               int* __restrict__ counts) {
    __shared__ int lh[NBUK];
    for (int j = threadIdx.x; j < NBUK; j += 256) lh[j] = 0;
    __syncthreads();
    int base = blockIdx.x * 2048;
#pragma unroll
    for (int k = 0; k < EPT; ++k) {
        int e = base + k * 256 + threadIdx.x;
        if (e < NE) atomicAdd(&lh[col[e] >> BKL], 1);
    }
    __syncthreads();
    for (int j = threadIdx.x; j < NBUK; j += 256)
        counts[j * EB + blockIdx.x] = lh[j];  // bucket-major
}

// ---------------- 2a. per-bucket scan (196 parallel blocks) ----------------
// counts row b -> bucket-relative exclusive prefix (in place); btot[b] = total.

__global__ __launch_bounds__(256) void k_scanA(int* __restrict__ counts,
                                               int* __restrict__ btot) {
    __shared__ int lds[256];
    const int b = blockIdx.x;
    const int t = threadIdx.x;
    int* c = counts + (size_t)b * EB;
    constexpr int PER = (EB + 255) / 256;  // 4
    int v[PER];
    int s = 0;
#pragma unroll
    for (int k = 0; k < PER; ++k) {
        int idx = t * PER + k;
        v[k] = (idx < EB) ? c[idx] : 0;
        s += v[k];
    }
    lds[t] = s;
    __syncthreads();
    for (int off = 1; off < 256; off <<= 1) {
        int u = (t >= off) ? lds[t - off] : 0;
        __syncthreads();
        lds[t] += u;
        __syncthreads();
    }
    int run = lds[t] - s;  // exclusive prefix of this thread's chunk
#pragma unroll
    for (int k = 0; k < PER; ++k) {
        int idx = t * PER + k;
        if (idx < EB) { c[idx] = run; run += v[k]; }
    }
    if (t == 255) btot[b] = lds[255];
}

// ---------------- 2b. scan of 196 bucket totals -> bstart ----------------

__global__ void k_scanB(const int* __restrict__ btot, int* __restrict__ bstart) {
    __shared__ int lds[256];
    int t = threadIdx.x;
    int v = (t < NBUK) ? btot[t] : 0;
    lds[t] = v;
    __syncthreads();
    for (int off = 1; off < 256; off <<= 1) {
        int u = (t >= off) ? lds[t - off] : 0;
        __syncthreads();
        lds[t] += u;
        __syncthreads();
    }
    if (t < NBUK) bstart[t] = lds[t] - v;  // exclusive
    if (t == 0) bstart[NBUK] = NE;
}

// ---------------- 3. stage records, bucket-grouped (LDS cursors) ----------
// record: .x = (c_local << 17) | r   (c_local<512: 9b, r<100000: 17b)
//         .y = edge weight bits
// cursor seed = bstart[bucket] + bucket-relative block offset.

__global__ __launch_bounds__(256) void k_A1(const int* __restrict__ row,
                                            const int* __restrict__ col,
                                            const float* __restrict__ ew,
                                            const int* __restrict__ counts,
                                            const int* __restrict__ bstart,
                                            int2* __restrict__ stg) {
    __shared__ int cur[NBUK];
    for (int j = threadIdx.x; j < NBUK; j += 256)
        cur[j] = bstart[j] + counts[j * EB + blockIdx.x];
    __syncthreads();
    int base = blockIdx.x * 2048;
#pragma unroll
    for (int k = 0; k < EPT; ++k) {
        int e = base + k * 256 + threadIdx.x;
        if (e < NE) {
            int c = col[e], r = row[e];
            int pos = atomicAdd(&cur[c >> BKL], 1);  // LDS atomic
            stg[pos] = make_int2(((c & 511) << 17) | r, __float_as_int(ew[e]));
        }
    }
}

// ---------------- 4. per-bucket degree -> dinv (plain stores) ----------

__global__ __launch_bounds__(256) void k_bdeg(const int* __restrict__ bstart,
                                              const int2* __restrict__ stg,
                                              float* __restrict__ dinv) {
    __shared__ float sdeg[512];
    const int b = blockIdx.x;
    for (int j = threadIdx.x; j < 512; j += 256) sdeg[j] = 0.0f;
    __syncthreads();
    const int s = bstart[b], e = bstart[b + 1];
    for (int p = s + threadIdx.x; p < e; p += 256) {
        int2 rec = stg[p];
        atomicAdd(&sdeg[rec.x >> 17], __int_as_float(rec.y));
    }
    __syncthreads();
    for (int j = threadIdx.x; j < 512; j += 256) {
        int idx = (b << BKL) + j;
        if (idx < NN) dinv[idx] = rsqrtf(sdeg[j] + 1.0f);  // +1 self-loop
    }
}

// ---------------- 5. per-bucket placement: offs + csw (LDS scan) ----------

__global__ __launch_bounds__(512) void k_place(const int* __restrict__ bstart,
                                               const int2* __restrict__ stg,
                                               const float* __restrict__ dinv,
                                               int* __restrict__ offs,
                                               int2* __restrict__ csw) {
    __shared__ int lcnt[512];
    __shared__ int cur[512];
    const int b = blockIdx.x;
    const int t = threadIdx.x;
    lcnt[t] = 0;
    __syncthreads();
    const int s = bstart[b], e = bstart[b + 1];
    for (int p = s + t; p < e; p += 512)
        atomicAdd(&lcnt[stg[p].x >> 17], 1);
    __syncthreads();
    int v = lcnt[t];
    for (int off = 1; off < 512; off <<= 1) {   // inclusive Hillis-Steele
        int u = (t >= off) ? lcnt[t - off] : 0;
        __syncthreads();
        lcnt[t] += u;
        __syncthreads();
    }
    int excl = lcnt[t] - v;
    int idx = (b << BKL) + t;
    if (idx <= NN) offs[idx] = s + excl;        // covers offs[NN] exactly once
    cur[t] = s + excl;
    __syncthreads();
    for (int p = s + t; p < e; p += 512) {
        int2 rec = stg[p];
        int cl = rec.x >> 17;
        int r = rec.x & 0x1FFFF;
        float nw = dinv[r] * __int_as_float(rec.y) * dinv[(b << BKL) + cl];
        int slot = atomicAdd(&cur[cl], 1);      // LDS atomic
        csw[slot] = make_int2(r, __float_as_int(nw));
    }
}

// ---------------- dense H = X * W ----------------
// Thread per node; acc[FOUT] in VGPRs; W loop-uniform -> s_load scalar reads.

template <int FIN, int FOUT>
__global__ __launch_bounds__(256) void k_matmul(const float* __restrict__ X,
                                                const float* __restrict__ W,
                                                float* __restrict__ H) {
    int i = blockIdx.x * 256 + threadIdx.x;
    if (i >= NN) return;
    const float* xr = X + (size_t)i * FIN;
    float acc[FOUT];
#pragma unroll
    for (int j = 0; j < FOUT; ++j) acc[j] = 0.0f;

    constexpr int KV = (FIN % 4 == 0) ? 4 : 2;
    for (int k = 0; k < FIN; k += KV) {
        float xv[KV];
        if constexpr (KV == 4) *(float4*)xv = *(const float4*)(xr + k);
        else                   *(float2*)xv = *(const float2*)(xr + k);
#pragma unroll
        for (int kk = 0; kk < KV; ++kk)
#pragma unroll
            for (int j = 0; j < FOUT; ++j)
                acc[j] = fmaf(xv[kk], W[(k + kk) * FOUT + j], acc[j]);
    }
    float* hr = H + (size_t)i * FOUT;
#pragma unroll
    for (int j = 0; j < FOUT; ++j) hr[j] = acc[j];
}

template <int FIN>
__global__ void k_matmul_1(const float* __restrict__ X, const float* __restrict__ W,
                           float* __restrict__ H) {
    int i = blockIdx.x * blockDim.x + threadIdx.x;
    if (i >= NN) return;
    const float* xr = X + (size_t)i * FIN;
    float acc = 0.0f;
#pragma unroll
    for (int k = 0; k < FIN; k += 2) {
        float2 xv = *(const float2*)(xr + k);
        acc = fmaf(xv.x, W[k], acc);
        acc = fmaf(xv.y, W[k + 1], acc);
    }
    H[i] = acc;
}

// ---------------- CSR pull aggregation + fused epilogue ----------------

template <int F, int LPN, bool RELU>
__global__ __launch_bounds__(256) void k_agg2(const int* __restrict__ offs,
                                              const int2* __restrict__ csw,
                                              const float* __restrict__ H,
                                              const float* __restrict__ dinv,
                                              const float* __restrict__ b,
                                              float* __restrict__ O) {
    constexpr int FH = F / 2;
    int t = blockIdx.x * blockDim.x + threadIdx.x;
    int g = t / LPN;
    int f = t - g * LPN;           // float2 lane
    if (g >= NN || f >= FH) return;
    int p = offs[g];
    const int pe = offs[g + 1];

    float2 a0 = {0.f, 0.f}, a1 = {0.f, 0.f}, a2 = {0.f, 0.f}, a3 = {0.f, 0.f};

    if (p < pe && (p & 1)) {       // peel to even p for 16B-aligned int4 loads
        int2 e = csw[p];
        float2 h = *(const float2*)(H + (size_t)e.x * F + 2 * f);
        float w = __int_as_float(e.y);
        a0.x = fmaf(h.x, w, a0.x); a0.y = fmaf(h.y, w, a0.y);
        ++p;
    }
    for (; p + 4 <= pe; p += 4) {
        int4 e01 = *(const int4*)(csw + p);
        int4 e23 = *(const int4*)(csw + p + 2);
        float2 h0 = *(const float2*)(H + (size_t)e01.x * F + 2 * f);
        float2 h1 = *(const float2*)(H + (size_t)e01.z * F + 2 * f);
        float2 h2 = *(const float2*)(H + (size_t)e23.x * F + 2 * f);
        float2 h3 = *(const float2*)(H + (size_t)e23.z * F + 2 * f);
        float w0 = __int_as_float(e01.y), w1 = __int_as_float(e01.w);
        float w2 = __int_as_float(e23.y), w3 = __int_as_float(e23.w);
        a0.x = fmaf(h0.x, w0, a0.x); a0.y = fmaf(h0.y, w0, a0.y);
        a1.x = fmaf(h1.x, w1, a1.x); a1.y = fmaf(h1.y, w1, a1.y);
        a2.x = fmaf(h2.x, w2, a2.x); a2.y = fmaf(h2.y, w2, a2.y);
        a3.x = fmaf(h3.x, w3, a3.x); a3.y = fmaf(h3.y, w3, a3.y);
    }
    for (; p < pe; ++p) {
        int2 e = csw[p];
        float2 h = *(const float2*)(H + (size_t)e.x * F + 2 * f);
        float w = __int_as_float(e.y);
        a0.x = fmaf(h.x, w, a0.x); a0.y = fmaf(h.y, w, a0.y);
    }

    float di = dinv[g];
    float d2 = di * di;
    float2 hs = *(const float2*)(H + (size_t)g * F + 2 * f);
    float2 bb = *(const float2*)(b + 2 * f);
    float vx = ((a0.x + a1.x) + (a2.x + a3.x)) + fmaf(hs.x, d2, bb.x);
    float vy = ((a0.y + a1.y) + (a2.y + a3.y)) + fmaf(hs.y, d2, bb.y);
    if (RELU) { vx = fmaxf(vx, 0.0f); vy = fmaxf(vy, 0.0f); }
    *(float2*)(O + (size_t)g * F + 2 * f) = make_float2(vx, vy);
}

__global__ void k_agg1(const int* __restrict__ offs, const int2* __restrict__ csw,
                       const float* __restrict__ H, const float* __restrict__ dinv,
                       const float* __restrict__ b, float* __restrict__ O) {
    int g = blockIdx.x * blockDim.x + threadIdx.x;
    if (g >= NN) return;
    int p = offs[g];
    const int pe = offs[g + 1];
    float a0 = 0.f, a1 = 0.f, a2 = 0.f, a3 = 0.f;
    for (; p + 4 <= pe; p += 4) {
        int2 e0 = csw[p], e1 = csw[p + 1], e2 = csw[p + 2], e3 = csw[p + 3];
        a0 = fmaf(H[e0.x], __int_as_float(e0.y), a0);
        a1 = fmaf(H[e1.x], __int_as_float(e1.y), a1);
        a2 = fmaf(H[e2.x], __int_as_float(e2.y), a2);
        a3 = fmaf(H[e3.x], __int_as_float(e3.y), a3);
    }
    for (; p < pe; ++p) {
        int2 e0 = csw[p];
        a0 = fmaf(H[e0.x], __int_as_float(e0.y), a0);
    }
    float di = dinv[g];
    O[g] = ((a0 + a1) + (a2 + a3)) + fmaf(H[g], di * di, b[0]);
}

// ---------------- launch ----------------

static inline size_t alignup(size_t x) { return (x + 255) & ~(size_t)255; }

extern "C" void kernel_launch(void* const* d_in, const int* in_sizes, int n_in,
                              void* d_out, int out_size, void* d_ws, size_t ws_size,
                              hipStream_t stream) {
    const float* x  = (const float*)d_in[0];
    const int*   ei = (const int*)d_in[1];
    const float* ew = (const float*)d_in[2];
    const float* Wp[7];
    const float* Bp[7];
    for (int l = 0; l < 7; ++l) {
        Wp[l] = (const float*)d_in[3 + 2 * l];
        Bp[l] = (const float*)d_in[4 + 2 * l];
    }
    const int* row = ei;       // source
    const int* col = ei + NE;  // destination

    // workspace carve (~88 MB)
    char* ws = (char*)d_ws;
    float* dinv  = (float*)ws;  ws += alignup((size_t)NN * 4);
    float* Hb    = (float*)ws;  ws += alignup((size_t)NN * 50 * 4);
    float* Aa    = (float*)ws;  ws += alignup((size_t)NN * 50 * 4);
    float* Ab    = (float*)ws;  ws += alignup((size_t)NN * 50 * 4);
    int*   offs  = (int*)ws;    ws += alignup((size_t)(NN + 1) * 4);
    int*   counts= (int*)ws;    ws += alignup((size_t)NBUK * EB * 4);
    int*   btot  = (int*)ws;    ws += alignup((size_t)NBUK * 4);
    int*   bstart= (int*)ws;    ws += alignup((size_t)(NBUK + 1) * 4);
    int2*  stg   = (int2*)ws;   ws += alignup((size_t)NE * 8);
    int2*  csw   = (int2*)ws;   ws += alignup((size_t)NE * 8);

    const int gN = (NN + 255) / 256;

    // CSR build — no global atomics, no single-block O(N) scans
    k_hist0<<<EB, 256, 0, stream>>>(col, counts);
    k_scanA<<<NBUK, 256, 0, stream>>>(counts, btot);
    k_scanB<<<1, 256, 0, stream>>>(btot, bstart);
    k_A1<<<EB, 256, 0, stream>>>(row, col, ew, counts, bstart, stg);
    k_bdeg<<<NBUK, 256, 0, stream>>>(bstart, stg, dinv);
    k_place<<<NBUK, 512, 0, stream>>>(bstart, stg, dinv, offs, csw);

#define LAYER(FIN, FOUT, LPN, RELU, XIN, OUT, LIDX)                                         \
    do {                                                                                    \
        k_matmul<FIN, FOUT><<<gN, 256, 0, stream>>>((XIN), Wp[LIDX], Hb);                   \
        k_agg2<FOUT, LPN, RELU><<<((size_t)NN * (LPN) + 255) / 256, 256, 0, stream>>>(      \
            offs, csw, Hb, dinv, Bp[LIDX], (OUT));                                          \
    } while (0)

    LAYER(128, 50, 32, true, x,  Aa, 0);
    LAYER(50,  50, 32, true, Aa, Ab, 1);
    LAYER(50,  30, 16, true, Ab, Aa, 2);
    LAYER(30,  30, 16, true, Aa, Ab, 3);
    LAYER(30,  10, 8,  true, Ab, Aa, 4);
    LAYER(10,  10, 8,  true, Aa, Ab, 5);
#undef LAYER

    // layer 7: 10 -> 1, no relu
    k_matmul_1<10><<<gN, 256, 0, stream>>>(Ab, Wp[6], Hb);
    k_agg1<<<gN, 256, 0, stream>>>(offs, csw, Hb, dinv, Bp[6], (float*)d_out);
}

// Round 10
// 508.135 us; speedup vs baseline: 1.7299x; 1.1742x over previous
//
#include <hip/hip_runtime.h>
#include <hip/hip_fp16.h>

// GCN, 7 layers: h = relu(Â (h W) + b), Â = D^-1/2 (A + I) D^-1/2.
// Round 10: agg gather traffic is the algorithmic floor (E x rowbytes); halve
// rowbytes by storing per-layer H in fp16 (fp32 accumulate, fp32 inter-layer
// activations). 8-way unrolled edge loop for more lines in flight.

static constexpr int NN = 100000;
static constexpr int NE = 1600000;
static constexpr int BKL = 9;                      // 512 nodes per bucket
static constexpr int NBUK = (NN + 511) >> BKL;     // 196 buckets
static constexpr int EPT = 8;                      // edges per thread (hist/A1)
static constexpr int EB = (NE + 2047) / 2048;      // 782 edge blocks

// ---------------- 1. bucket histogram (LDS only) ----------------

__global__ __launch_bounds__(256) void k_hist0(const int* __restrict__ col,
                                               int* __restrict__ counts) {
    __shared__ int lh[NBUK];
    for (int j = threadIdx.x; j < NBUK; j += 256) lh[j] = 0;
    __syncthreads();
    int base = blockIdx.x * 2048;
#pragma unroll
    for (int k = 0; k < EPT; ++k) {
        int e = base + k * 256 + threadIdx.x;
        if (e < NE) atomicAdd(&lh[col[e] >> BKL], 1);
    }
    __syncthreads();
    for (int j = threadIdx.x; j < NBUK; j += 256)
        counts[j * EB + blockIdx.x] = lh[j];  // bucket-major
}

// ---------------- 2a. per-bucket scan (196 parallel blocks) ----------------

__global__ __launch_bounds__(256) void k_scanA(int* __restrict__ counts,
                                               int* __restrict__ btot) {
    __shared__ int lds[256];
    const int b = blockIdx.x;
    const int t = threadIdx.x;
    int* c = counts + (size_t)b * EB;
    constexpr int PER = (EB + 255) / 256;  // 4
    int v[PER];
    int s = 0;
#pragma unroll
    for (int k = 0; k < PER; ++k) {
        int idx = t * PER + k;
        v[k] = (idx < EB) ? c[idx] : 0;
        s += v[k];
    }
    lds[t] = s;
    __syncthreads();
    for (int off = 1; off < 256; off <<= 1) {
        int u = (t >= off) ? lds[t - off] : 0;
        __syncthreads();
        lds[t] += u;
        __syncthreads();
    }
    int run = lds[t] - s;
#pragma unroll
    for (int k = 0; k < PER; ++k) {
        int idx = t * PER + k;
        if (idx < EB) { c[idx] = run; run += v[k]; }
    }
    if (t == 255) btot[b] = lds[255];
}

// ---------------- 2b. scan of 196 bucket totals -> bstart ----------------

__global__ void k_scanB(const int* __restrict__ btot, int* __restrict__ bstart) {
    __shared__ int lds[256];
    int t = threadIdx.x;
    int v = (t < NBUK) ? btot[t] : 0;
    lds[t] = v;
    __syncthreads();
    for (int off = 1; off < 256; off <<= 1) {
        int u = (t >= off) ? lds[t - off] : 0;
        __syncthreads();
        lds[t] += u;
        __syncthreads();
    }
    if (t < NBUK) bstart[t] = lds[t] - v;  // exclusive
    if (t == 0) bstart[NBUK] = NE;
}

// ---------------- 3. stage records, bucket-grouped (LDS cursors) ----------

__global__ __launch_bounds__(256) void k_A1(const int* __restrict__ row,
                                            const int* __restrict__ col,
                                            const float* __restrict__ ew,
                                            const int* __restrict__ counts,
                                            const int* __restrict__ bstart,
                                            int2* __restrict__ stg) {
    __shared__ int cur[NBUK];
    for (int j = threadIdx.x; j < NBUK; j += 256)
        cur[j] = bstart[j] + counts[j * EB + blockIdx.x];
    __syncthreads();
    int base = blockIdx.x * 2048;
#pragma unroll
    for (int k = 0; k < EPT; ++k) {
        int e = base + k * 256 + threadIdx.x;
        if (e < NE) {
            int c = col[e], r = row[e];
            int pos = atomicAdd(&cur[c >> BKL], 1);  // LDS atomic
            stg[pos] = make_int2(((c & 511) << 17) | r, __float_as_int(ew[e]));
        }
    }
}

// ---------------- 4. per-bucket degree -> dinv (plain stores) ----------

__global__ __launch_bounds__(256) void k_bdeg(const int* __restrict__ bstart,
                                              const int2* __restrict__ stg,
                                              float* __restrict__ dinv) {
    __shared__ float sdeg[512];
    const int b = blockIdx.x;
    for (int j = threadIdx.x; j < 512; j += 256) sdeg[j] = 0.0f;
    __syncthreads();
    const int s = bstart[b], e = bstart[b + 1];
    for (int p = s + threadIdx.x; p < e; p += 256) {
        int2 rec = stg[p];
        atomicAdd(&sdeg[rec.x >> 17], __int_as_float(rec.y));
    }
    __syncthreads();
    for (int j = threadIdx.x; j < 512; j += 256) {
        int idx = (b << BKL) + j;
        if (idx < NN) dinv[idx] = rsqrtf(sdeg[j] + 1.0f);  // +1 self-loop
    }
}

// ---------------- 5. per-bucket placement: offs + csw (LDS scan) ----------

__global__ __launch_bounds__(512) void k_place(const int* __restrict__ bstart,
                                               const int2* __restrict__ stg,
                                               const float* __restrict__ dinv,
                                               int* __restrict__ offs,
                                               int2* __restrict__ csw) {
    __shared__ int lcnt[512];
    __shared__ int cur[512];
    const int b = blockIdx.x;
    const int t = threadIdx.x;
    lcnt[t] = 0;
    __syncthreads();
    const int s = bstart[b], e = bstart[b + 1];
    for (int p = s + t; p < e; p += 512)
        atomicAdd(&lcnt[stg[p].x >> 17], 1);
    __syncthreads();
    int v = lcnt[t];
    for (int off = 1; off < 512; off <<= 1) {   // inclusive Hillis-Steele
        int u = (t >= off) ? lcnt[t - off] : 0;
        __syncthreads();
        lcnt[t] += u;
        __syncthreads();
    }
    int excl = lcnt[t] - v;
    int idx = (b << BKL) + t;
    if (idx <= NN) offs[idx] = s + excl;        // covers offs[NN] exactly once
    cur[t] = s + excl;
    __syncthreads();
    for (int p = s + t; p < e; p += 512) {
        int2 rec = stg[p];
        int cl = rec.x >> 17;
        int r = rec.x & 0x1FFFF;
        float nw = dinv[r] * __int_as_float(rec.y) * dinv[(b << BKL) + cl];
        int slot = atomicAdd(&cur[cl], 1);      // LDS atomic
        csw[slot] = make_int2(r, __float_as_int(nw));
    }
}

// ---------------- dense H = X * W (fp32 in, fp16 out) ----------------

template <int FIN, int FOUT>
__global__ __launch_bounds__(256) void k_matmul(const float* __restrict__ X,
                                                const float* __restrict__ W,
                                                __half2* __restrict__ H) {
    int i = blockIdx.x * 256 + threadIdx.x;
    if (i >= NN) return;
    const float* xr = X + (size_t)i * FIN;
    float acc[FOUT];
#pragma unroll
    for (int j = 0; j < FOUT; ++j) acc[j] = 0.0f;

    constexpr int KV = (FIN % 4 == 0) ? 4 : 2;
    for (int k = 0; k < FIN; k += KV) {
        float xv[KV];
        if constexpr (KV == 4) *(float4*)xv = *(const float4*)(xr + k);
        else                   *(float2*)xv = *(const float2*)(xr + k);
#pragma unroll
        for (int kk = 0; kk < KV; ++kk)
#pragma unroll
            for (int j = 0; j < FOUT; ++j)
                acc[j] = fmaf(xv[kk], W[(k + kk) * FOUT + j], acc[j]);
    }
    __half2* hr = H + (size_t)i * (FOUT / 2);
#pragma unroll
    for (int j = 0; j < FOUT / 2; ++j)
        hr[j] = __floats2half2_rn(acc[2 * j], acc[2 * j + 1]);
}

// final layer 10 -> 1 (fp32 H)
template <int FIN>
__global__ void k_matmul_1(const float* __restrict__ X, const float* __restrict__ W,
                           float* __restrict__ H) {
    int i = blockIdx.x * blockDim.x + threadIdx.x;
    if (i >= NN) return;
    const float* xr = X + (size_t)i * FIN;
    float acc = 0.0f;
#pragma unroll
    for (int k = 0; k < FIN; k += 2) {
        float2 xv = *(const float2*)(xr + k);
        acc = fmaf(xv.x, W[k], acc);
        acc = fmaf(xv.y, W[k + 1], acc);
    }
    H[i] = acc;
}

// ---------------- CSR pull aggregation + fused epilogue (fp16 H) ----------
// LPN lanes per node; lane f handles half2 feature pair f. 8-way unrolled
// edge loop: 4x int4 record loads + 8 half2 gathers in flight.

template <int F, int LPN, bool RELU>
__global__ __launch_bounds__(256) void k_agg2(const int* __restrict__ offs,
                                              const int2* __restrict__ csw,
                                              const __half2* __restrict__ H,
                                              const float* __restrict__ dinv,
                                              const float* __restrict__ b,
                                              float* __restrict__ O) {
    constexpr int FH = F / 2;
    int t = blockIdx.x * blockDim.x + threadIdx.x;
    int g = t / LPN;
    int f = t - g * LPN;           // half2 lane
    if (g >= NN || f >= FH) return;
    int p = offs[g];
    const int pe = offs[g + 1];

    float2 a0 = {0.f, 0.f}, a1 = {0.f, 0.f}, a2 = {0.f, 0.f}, a3 = {0.f, 0.f};

    if (p < pe && (p & 1)) {       // peel to even p for 16B-aligned int4 loads
        int2 e = csw[p];
        float2 h = __half22float2(H[(size_t)e.x * FH + f]);
        float w = __int_as_float(e.y);
        a0.x = fmaf(h.x, w, a0.x); a0.y = fmaf(h.y, w, a0.y);
        ++p;
    }
    for (; p + 8 <= pe; p += 8) {
        int4 e01 = *(const int4*)(csw + p);
        int4 e23 = *(const int4*)(csw + p + 2);
        int4 e45 = *(const int4*)(csw + p + 4);
        int4 e67 = *(const int4*)(csw + p + 6);
        float2 h0 = __half22float2(H[(size_t)e01.x * FH + f]);
        float2 h1 = __half22float2(H[(size_t)e01.z * FH + f]);
        float2 h2 = __half22float2(H[(size_t)e23.x * FH + f]);
        float2 h3 = __half22float2(H[(size_t)e23.z * FH + f]);
        float2 h4 = __half22float2(H[(size_t)e45.x * FH + f]);
        float2 h5 = __half22float2(H[(size_t)e45.z * FH + f]);
        float2 h6 = __half22float2(H[(size_t)e67.x * FH + f]);
        float2 h7 = __half22float2(H[(size_t)e67.z * FH + f]);
        float w0 = __int_as_float(e01.y), w1 = __int_as_float(e01.w);
        float w2 = __int_as_float(e23.y), w3 = __int_as_float(e23.w);
        float w4 = __int_as_float(e45.y), w5 = __int_as_float(e45.w);
        float w6 = __int_as_float(e67.y), w7 = __int_as_float(e67.w);
        a0.x = fmaf(h0.x, w0, a0.x); a0.y = fmaf(h0.y, w0, a0.y);
        a1.x = fmaf(h1.x, w1, a1.x); a1.y = fmaf(h1.y, w1, a1.y);
        a2.x = fmaf(h2.x, w2, a2.x); a2.y = fmaf(h2.y, w2, a2.y);
        a3.x = fmaf(h3.x, w3, a3.x); a3.y = fmaf(h3.y, w3, a3.y);
        a0.x = fmaf(h4.x, w4, a0.x); a0.y = fmaf(h4.y, w4, a0.y);
        a1.x = fmaf(h5.x, w5, a1.x); a1.y = fmaf(h5.y, w5, a1.y);
        a2.x = fmaf(h6.x, w6, a2.x); a2.y = fmaf(h6.y, w6, a2.y);
        a3.x = fmaf(h7.x, w7, a3.x); a3.y = fmaf(h7.y, w7, a3.y);
    }
    for (; p < pe; ++p) {
        int2 e = csw[p];
        float2 h = __half22float2(H[(size_t)e.x * FH + f]);
        float w = __int_as_float(e.y);
        a0.x = fmaf(h.x, w, a0.x); a0.y = fmaf(h.y, w, a0.y);
    }

    float di = dinv[g];
    float d2 = di * di;
    float2 hs = __half22float2(H[(size_t)g * FH + f]);
    float2 bb = *(const float2*)(b + 2 * f);
    float vx = ((a0.x + a1.x) + (a2.x + a3.x)) + fmaf(hs.x, d2, bb.x);
    float vy = ((a0.y + a1.y) + (a2.y + a3.y)) + fmaf(hs.y, d2, bb.y);
    if (RELU) { vx = fmaxf(vx, 0.0f); vy = fmaxf(vy, 0.0f); }
    *(float2*)(O + (size_t)g * F + 2 * f) = make_float2(vx, vy);
}

// F=1 aggregation (final layer, fp32 H): one thread per node.
__global__ void k_agg1(const int* __restrict__ offs, const int2* __restrict__ csw,
                       const float* __restrict__ H, const float* __restrict__ dinv,
                       const float* __restrict__ b, float* __restrict__ O) {
    int g = blockIdx.x * blockDim.x + threadIdx.x;
    if (g >= NN) return;
    int p = offs[g];
    const int pe = offs[g + 1];
    float a0 = 0.f, a1 = 0.f, a2 = 0.f, a3 = 0.f;
    for (; p + 4 <= pe; p += 4) {
        int2 e0 = csw[p], e1 = csw[p + 1], e2 = csw[p + 2], e3 = csw[p + 3];
        a0 = fmaf(H[e0.x], __int_as_float(e0.y), a0);
        a1 = fmaf(H[e1.x], __int_as_float(e1.y), a1);
        a2 = fmaf(H[e2.x], __int_as_float(e2.y), a2);
        a3 = fmaf(H[e3.x], __int_as_float(e3.y), a3);
    }
    for (; p < pe; ++p) {
        int2 e0 = csw[p];
        a0 = fmaf(H[e0.x], __int_as_float(e0.y), a0);
    }
    float di = dinv[g];
    O[g] = ((a0 + a1) + (a2 + a3)) + fmaf(H[g], di * di, b[0]);
}

// ---------------- launch ----------------

static inline size_t alignup(size_t x) { return (x + 255) & ~(size_t)255; }

extern "C" void kernel_launch(void* const* d_in, const int* in_sizes, int n_in,
                              void* d_out, int out_size, void* d_ws, size_t ws_size,
                              hipStream_t stream) {
    const float* x  = (const float*)d_in[0];
    const int*   ei = (const int*)d_in[1];
    const float* ew = (const float*)d_in[2];
    const float* Wp[7];
    const float* Bp[7];
    for (int l = 0; l < 7; ++l) {
        Wp[l] = (const float*)d_in[3 + 2 * l];
        Bp[l] = (const float*)d_in[4 + 2 * l];
    }
    const int* row = ei;       // source
    const int* col = ei + NE;  // destination

    // workspace carve (~80 MB). Hb sized for fp32 F=1 reuse (400 KB min);
    // fp16 F=50 needs NN*50*2 = 10 MB -> allocate 10 MB.
    char* ws = (char*)d_ws;
    float* dinv  = (float*)ws;  ws += alignup((size_t)NN * 4);
    char*  Hb    = ws;          ws += alignup((size_t)NN * 50 * 2);
    float* Aa    = (float*)ws;  ws += alignup((size_t)NN * 50 * 4);
    float* Ab    = (float*)ws;  ws += alignup((size_t)NN * 50 * 4);
    int*   offs  = (int*)ws;    ws += alignup((size_t)(NN + 1) * 4);
    int*   counts= (int*)ws;    ws += alignup((size_t)NBUK * EB * 4);
    int*   btot  = (int*)ws;    ws += alignup((size_t)NBUK * 4);
    int*   bstart= (int*)ws;    ws += alignup((size_t)(NBUK + 1) * 4);
    int2*  stg   = (int2*)ws;   ws += alignup((size_t)NE * 8);
    int2*  csw   = (int2*)ws;   ws += alignup((size_t)NE * 8);

    const int gN = (NN + 255) / 256;

    // CSR build — no global atomics, no single-block O(N) scans
    k_hist0<<<EB, 256, 0, stream>>>(col, counts);
    k_scanA<<<NBUK, 256, 0, stream>>>(counts, btot);
    k_scanB<<<1, 256, 0, stream>>>(btot, bstart);
    k_A1<<<EB, 256, 0, stream>>>(row, col, ew, counts, bstart, stg);
    k_bdeg<<<NBUK, 256, 0, stream>>>(bstart, stg, dinv);
    k_place<<<NBUK, 512, 0, stream>>>(bstart, stg, dinv, offs, csw);

#define LAYER(FIN, FOUT, LPN, RELU, XIN, OUT, LIDX)                                         \
    do {                                                                                    \
        k_matmul<FIN, FOUT><<<gN, 256, 0, stream>>>((XIN), Wp[LIDX], (__half2*)Hb);         \
        k_agg2<FOUT, LPN, RELU><<<((size_t)NN * (LPN) + 255) / 256, 256, 0, stream>>>(      \
            offs, csw, (const __half2*)Hb, dinv, Bp[LIDX], (OUT));                          \
    } while (0)

    LAYER(128, 50, 32, true, x,  Aa, 0);
    LAYER(50,  50, 32, true, Aa, Ab, 1);
    LAYER(50,  30, 16, true, Ab, Aa, 2);
    LAYER(30,  30, 16, true, Aa, Ab, 3);
    LAYER(30,  10, 8,  true, Ab, Aa, 4);
    LAYER(10,  10, 8,  true, Aa, Ab, 5);
#undef LAYER

    // layer 7: 10 -> 1, no relu, fp32 H
    k_matmul_1<10><<<gN, 256, 0, stream>>>(Ab, Wp[6], (float*)Hb);
    k_agg1<<<gN, 256, 0, stream>>>(offs, csw, (const float*)Hb, dinv, Bp[6],
                                   (float*)d_out);
}